// Round 5
// baseline (667.140 us; speedup 1.0000x reference)
//
#include <hip/hip_runtime.h>
#include <hip/hip_bf16.h>

#define HDIM 1024
#define SEQ  2048
#define BATCH 32
#define M_TOTAL (BATCH * SEQ)   // 65536
#define BM 128
#define BN 256
#define BK 32
#define NSLICE 8                // (HDIM/BN)=4 n-blocks x 2 n-waves

typedef __bf16 bf16x8 __attribute__((ext_vector_type(8)));
typedef float  f32x4  __attribute__((ext_vector_type(4)));
typedef unsigned short u16;
#define AS1 __attribute__((address_space(1)))
#define AS3 __attribute__((address_space(3)))

__device__ __forceinline__ u16 f2bf(float f) {
    unsigned int u = __float_as_uint(f);
    u += 0x7FFFu + ((u >> 16) & 1u);   // round-to-nearest-even
    return (u16)(u >> 16);
}

// ---- fp32 -> bf16, 8 elems/thread ----
__global__ __launch_bounds__(256) void cvt_kernel(const float* __restrict__ in,
                                                  u16* __restrict__ out) {
    size_t i = ((size_t)blockIdx.x * 256 + threadIdx.x) * 8;
    float4 f0 = *(const float4*)(in + i);
    float4 f1 = *(const float4*)(in + i + 4);
    uint4 v;
    v.x = (unsigned)f2bf(f0.x) | ((unsigned)f2bf(f0.y) << 16);
    v.y = (unsigned)f2bf(f0.z) | ((unsigned)f2bf(f0.w) << 16);
    v.z = (unsigned)f2bf(f1.x) | ((unsigned)f2bf(f1.y) << 16);
    v.w = (unsigned)f2bf(f1.z) | ((unsigned)f2bf(f1.w) << 16);
    *(uint4*)(out + i) = v;
}

// ---- qb[b][o] = query[b]·Wa_w[o] + Wa_b[o] + Ua_b[o] (fp32) ----
__global__ __launch_bounds__(256) void qb_kernel(const float* __restrict__ query,
                                                 const float* __restrict__ Wa_w,
                                                 const float* __restrict__ Wa_b,
                                                 const float* __restrict__ Ua_b,
                                                 float* __restrict__ qb) {
    __shared__ float qs[HDIM];
    const int b = blockIdx.x;
    const int tid = threadIdx.x;
    ((float4*)qs)[tid] = ((const float4*)(query + b * HDIM))[tid];
    __syncthreads();
    const int lane = tid & 63;
    const int w = tid >> 6;
    const int obase = blockIdx.y * 64 + w * 16;
    for (int i = 0; i < 16; i++) {
        int o = obase + i;
        const float4* wrow = (const float4*)(Wa_w + (size_t)o * HDIM);
        float s = 0.f;
        #pragma unroll
        for (int j = 0; j < 4; j++) {
            float4 wv = wrow[j * 64 + lane];
            float4 qv = ((const float4*)qs)[j * 64 + lane];
            s += wv.x * qv.x + wv.y * qv.y + wv.z * qv.z + wv.w * qv.w;
        }
        #pragma unroll
        for (int m = 1; m < 64; m <<= 1) s += __shfl_xor(s, m);
        if (lane == 0) qb[b * HDIM + o] = s + Wa_b[o] + Ua_b[o];
    }
}

// ---- GEMM keysb·Ua^T + fused tanh + Va dot -> deterministic score slices ----
// grid (HDIM/BN=4, M_TOTAL/BM=512) n-major, block 256 (4 waves, each 64x128)
__global__ __launch_bounds__(256, 2) void gemm_score_kernel(const u16* __restrict__ keysb,
                                                            const u16* __restrict__ uab,
                                                            const float* __restrict__ qb,
                                                            const float* __restrict__ vaw,
                                                            float* __restrict__ sp) {
    __shared__ __align__(16) u16 As[BM * BK];   //  8 KB
    __shared__ __align__(16) u16 Bs[BN * BK];   // 16 KB
    const int tid  = threadIdx.x;
    const int lane = tid & 63;
    const int w    = tid >> 6;
    const int n0 = blockIdx.x * BN;
    const int m0 = blockIdx.y * BM;
    const int wave_m = (w & 1) * 64;
    const int wave_n = (w >> 1) * 128;

    f32x4 acc[4][8] = {};

    const int srow = lane >> 2;            // 16 rows per gl_lds instr
    const int scol = (lane & 3) * 8;
    const u16* gA = keysb + (size_t)(m0 + w * 32 + srow) * HDIM + scol;
    const u16* gB = uab   + (size_t)(n0 + w * 64 + srow) * HDIM + scol;
    u16* lA = As + (w * 32) * BK;          // wave-uniform bases
    u16* lB = Bs + (w * 64) * BK;

    const int fr = lane & 15;
    const int fq = lane >> 4;

    for (int k0 = 0; k0 < HDIM; k0 += BK) {
        __syncthreads();
        #pragma unroll
        for (int i = 0; i < 2; i++)        // 32 A rows per wave
            __builtin_amdgcn_global_load_lds((AS1 void*)(gA + k0 + i * 16 * HDIM),
                                             (AS3 void*)(lA + i * 16 * BK), 16, 0, 0);
        #pragma unroll
        for (int i = 0; i < 4; i++)        // 64 B rows per wave
            __builtin_amdgcn_global_load_lds((AS1 void*)(gB + k0 + i * 16 * HDIM),
                                             (AS3 void*)(lB + i * 16 * BK), 16, 0, 0);
        __syncthreads();

        bf16x8 a[4], b[8];
        #pragma unroll
        for (int i = 0; i < 4; i++)
            a[i] = *(const bf16x8*)(As + (wave_m + i * 16 + fr) * BK + fq * 8);
        #pragma unroll
        for (int i = 0; i < 8; i++)
            b[i] = *(const bf16x8*)(Bs + (wave_n + i * 16 + fr) * BK + fq * 8);
        #pragma unroll
        for (int mi = 0; mi < 4; mi++)
            #pragma unroll
            for (int ni = 0; ni < 8; ni++)
                acc[mi][ni] = __builtin_amdgcn_mfma_f32_16x16x32_bf16(a[mi], b[ni], acc[mi][ni], 0, 0, 0);
    }

    // epilogue: h = tanh(acc + qb), partial score over 128 n-cols -> slice write
    const int bidx = m0 >> 11;   // BM=128 divides SEQ=2048
    float qv[8], vv[8];
    #pragma unroll
    for (int ni = 0; ni < 8; ni++) {
        int n_g = n0 + wave_n + ni * 16 + fr;
        qv[ni] = qb[bidx * HDIM + n_g];
        vv[ni] = vaw[n_g];
    }
    const int slice = blockIdx.x * 2 + (w >> 1);
    float* sl = sp + ((size_t)slice * BATCH + bidx) * SEQ;
    #pragma unroll
    for (int mi = 0; mi < 4; mi++) {
        #pragma unroll
        for (int r = 0; r < 4; r++) {
            float p = 0.f;
            #pragma unroll
            for (int ni = 0; ni < 8; ni++) {
                float x = acc[mi][ni][r] + qv[ni];
                float e = __expf(2.f * x);          // tanh = 1 - 2/(e^{2x}+1), NaN-free
                p += (1.f - 2.f / (e + 1.f)) * vv[ni];
            }
            p += __shfl_xor(p, 1);
            p += __shfl_xor(p, 2);
            p += __shfl_xor(p, 4);
            p += __shfl_xor(p, 8);
            if (fr == 0) {
                int s_g = (m0 + wave_m + mi * 16 + fq * 4 + r) & (SEQ - 1);
                sl[s_g] = p;
            }
        }
    }
}

// ---- softmax over SEQ per batch; sums 8 slices; zeroes ctx region ----
__global__ __launch_bounds__(256) void softmax_kernel(const float* __restrict__ sp,
                                                      float* __restrict__ weights,
                                                      float* __restrict__ ctx) {
    __shared__ float red[4];
    const int b = blockIdx.x;
    const int tid = threadIdx.x;
    float4 z = {0.f, 0.f, 0.f, 0.f};
    ((float4*)(ctx + b * HDIM))[tid] = z;       // zero context for atomics
    float v[8];
    float mx = -1e30f;
    #pragma unroll
    for (int i = 0; i < 8; i++) {
        int s = tid + i * 256;
        float a = 0.f;
        #pragma unroll
        for (int j = 0; j < NSLICE; j++) a += sp[((size_t)j * BATCH + b) * SEQ + s];
        v[i] = a;
        mx = fmaxf(mx, a);
    }
    #pragma unroll
    for (int m = 1; m < 64; m <<= 1) mx = fmaxf(mx, __shfl_xor(mx, m));
    if ((tid & 63) == 0) red[tid >> 6] = mx;
    __syncthreads();
    mx = fmaxf(fmaxf(red[0], red[1]), fmaxf(red[2], red[3]));
    float sum = 0.f;
    #pragma unroll
    for (int i = 0; i < 8; i++) { v[i] = __expf(v[i] - mx); sum += v[i]; }
    #pragma unroll
    for (int m = 1; m < 64; m <<= 1) sum += __shfl_xor(sum, m);
    __syncthreads();
    if ((tid & 63) == 0) red[tid >> 6] = sum;
    __syncthreads();
    sum = red[0] + red[1] + red[2] + red[3];
    float inv = 1.f / sum;
    #pragma unroll
    for (int i = 0; i < 8; i++) weights[b * SEQ + tid + i * 256] = v[i] * inv;
}

// ---- context[b][h] = sum_s w[b][s] * keysb[b][s][h] (bf16 keys) ----
// grid (BATCH, SEQ/64), block 256.
// Thread tid -> h-group (tid&127)*8 (128 groups x 8 bf16 = 1024 = HDIM),
// s-half (tid>>7)*32. Two threads per h-group, atomics into pre-zeroed ctx.
__global__ __launch_bounds__(256) void context_kernel(const u16* __restrict__ keysb,
                                                      const float* __restrict__ weights,
                                                      float* __restrict__ ctx) {
    __shared__ float wsm[64];
    const int b = blockIdx.x;
    const int s0 = blockIdx.y * 64;
    const int tid = threadIdx.x;
    if (tid < 64) wsm[tid] = weights[b * SEQ + s0 + tid];
    __syncthreads();
    const int hq = tid & 127;
    const int sh = (tid >> 7) * 32;
    float a0 = 0.f, a1 = 0.f, a2 = 0.f, a3 = 0.f;
    float a4 = 0.f, a5 = 0.f, a6 = 0.f, a7 = 0.f;
    const uint4* kp = (const uint4*)(keysb + (size_t)b * SEQ * HDIM
                                     + (size_t)(s0 + sh) * HDIM) + hq;
    #pragma unroll 8
    for (int s = 0; s < 32; s++) {
        uint4 kv = kp[s * 128];            // row stride = 1024 u16 = 128 uint4
        float wv = wsm[sh + s];
        a0 += wv * __uint_as_float(kv.x << 16);
        a1 += wv * __uint_as_float(kv.x & 0xFFFF0000u);
        a2 += wv * __uint_as_float(kv.y << 16);
        a3 += wv * __uint_as_float(kv.y & 0xFFFF0000u);
        a4 += wv * __uint_as_float(kv.z << 16);
        a5 += wv * __uint_as_float(kv.z & 0xFFFF0000u);
        a6 += wv * __uint_as_float(kv.w << 16);
        a7 += wv * __uint_as_float(kv.w & 0xFFFF0000u);
    }
    float* o = ctx + b * HDIM + hq * 8;
    atomicAdd(o + 0, a0);
    atomicAdd(o + 1, a1);
    atomicAdd(o + 2, a2);
    atomicAdd(o + 3, a3);
    atomicAdd(o + 4, a4);
    atomicAdd(o + 5, a5);
    atomicAdd(o + 6, a6);
    atomicAdd(o + 7, a7);
}

extern "C" void kernel_launch(void* const* d_in, const int* in_sizes, int n_in,
                              void* d_out, int out_size, void* d_ws, size_t ws_size,
                              hipStream_t stream) {
    const float* query = (const float*)d_in[0];
    const float* keys  = (const float*)d_in[1];
    const float* Wa_w  = (const float*)d_in[2];
    const float* Wa_b  = (const float*)d_in[3];
    const float* Ua_w  = (const float*)d_in[4];
    const float* Ua_b  = (const float*)d_in[5];
    const float* Va_w  = (const float*)d_in[6];
    // Va_b unused: softmax is shift-invariant.
    float* out = (float*)d_out;   // [0, 32768) context, [32768, 98304) weights

    char* ws = (char*)d_ws;
    u16*  keysb = (u16*)ws;                                     // 134217728 B
    u16*  uab   = (u16*)(ws + 134217728);                       //   2097152 B
    float* qb   = (float*)(ws + 134217728 + 2097152);           //    131072 B
    float* sp   = (float*)(ws + 134217728 + 2097152 + 131072);  //   2097152 B

    cvt_kernel<<<(BATCH * SEQ * HDIM) / 2048, 256, 0, stream>>>(keys, keysb);
    cvt_kernel<<<(HDIM * HDIM) / 2048, 256, 0, stream>>>(Ua_w, uab);
    qb_kernel<<<dim3(BATCH, HDIM / 64), 256, 0, stream>>>(query, Wa_w, Wa_b, Ua_b, qb);
    gemm_score_kernel<<<dim3(HDIM / BN, M_TOTAL / BM), 256, 0, stream>>>(keysb, uab, qb, Va_w, sp);
    softmax_kernel<<<BATCH, 256, 0, stream>>>(sp, out + BATCH * HDIM, out);
    context_kernel<<<dim3(BATCH, SEQ / 64), 256, 0, stream>>>(keysb, out + BATCH * HDIM, out);
}

// Round 6
// 623.790 us; speedup vs baseline: 1.0695x; 1.0695x over previous
//
#include <hip/hip_runtime.h>
#include <hip/hip_bf16.h>

#define HDIM 1024
#define SEQ  2048
#define BATCH 32
#define M_TOTAL (BATCH * SEQ)   // 65536
#define BM 128
#define BN 256
#define BK 64
#define NSLICE 8                // (HDIM/BN)=4 n-blocks x 2 n-waves

typedef __bf16 bf16x8 __attribute__((ext_vector_type(8)));
typedef float  f32x4  __attribute__((ext_vector_type(4)));
typedef unsigned short u16;
#define AS1 __attribute__((address_space(1)))
#define AS3 __attribute__((address_space(3)))

__device__ __forceinline__ u16 f2bf(float f) {
    unsigned int u = __float_as_uint(f);
    u += 0x7FFFu + ((u >> 16) & 1u);   // round-to-nearest-even
    return (u16)(u >> 16);
}

// ---- fp32 -> bf16, 8 elems/thread ----
__global__ __launch_bounds__(256) void cvt_kernel(const float* __restrict__ in,
                                                  u16* __restrict__ out) {
    size_t i = ((size_t)blockIdx.x * 256 + threadIdx.x) * 8;
    float4 f0 = *(const float4*)(in + i);
    float4 f1 = *(const float4*)(in + i + 4);
    uint4 v;
    v.x = (unsigned)f2bf(f0.x) | ((unsigned)f2bf(f0.y) << 16);
    v.y = (unsigned)f2bf(f0.z) | ((unsigned)f2bf(f0.w) << 16);
    v.z = (unsigned)f2bf(f1.x) | ((unsigned)f2bf(f1.y) << 16);
    v.w = (unsigned)f2bf(f1.z) | ((unsigned)f2bf(f1.w) << 16);
    *(uint4*)(out + i) = v;
}

// ---- qb[b][o] = query[b]·Wa_w[o] + Wa_b[o] + Ua_b[o] (fp32) ----
__global__ __launch_bounds__(256) void qb_kernel(const float* __restrict__ query,
                                                 const float* __restrict__ Wa_w,
                                                 const float* __restrict__ Wa_b,
                                                 const float* __restrict__ Ua_b,
                                                 float* __restrict__ qb) {
    __shared__ float qs[HDIM];
    const int b = blockIdx.x;
    const int tid = threadIdx.x;
    ((float4*)qs)[tid] = ((const float4*)(query + b * HDIM))[tid];
    __syncthreads();
    const int lane = tid & 63;
    const int w = tid >> 6;
    const int obase = blockIdx.y * 64 + w * 16;
    for (int i = 0; i < 16; i++) {
        int o = obase + i;
        const float4* wrow = (const float4*)(Wa_w + (size_t)o * HDIM);
        float s = 0.f;
        #pragma unroll
        for (int j = 0; j < 4; j++) {
            float4 wv = wrow[j * 64 + lane];
            float4 qv = ((const float4*)qs)[j * 64 + lane];
            s += wv.x * qv.x + wv.y * qv.y + wv.z * qv.z + wv.w * qv.w;
        }
        #pragma unroll
        for (int m = 1; m < 64; m <<= 1) s += __shfl_xor(s, m);
        if (lane == 0) qb[b * HDIM + o] = s + Wa_b[o] + Ua_b[o];
    }
}

// ---- GEMM keysb·Ua^T + fused tanh + Va dot -> deterministic score slices ----
// grid (HDIM/BN=4, M_TOTAL/BM=512) n-major, block 256 (4 waves, each 64x128)
// BK=64: half the barrier pairs of BK=32 (barrier drain was ~35% of cycles)
__global__ __launch_bounds__(256, 2) void gemm_score_kernel(const u16* __restrict__ keysb,
                                                            const u16* __restrict__ uab,
                                                            const float* __restrict__ qb,
                                                            const float* __restrict__ vaw,
                                                            float* __restrict__ sp) {
    __shared__ __align__(16) u16 As[BM * BK];   // 16 KB
    __shared__ __align__(16) u16 Bs[BN * BK];   // 32 KB
    const int tid  = threadIdx.x;
    const int lane = tid & 63;
    const int w    = tid >> 6;
    const int n0 = blockIdx.x * BN;
    const int m0 = blockIdx.y * BM;
    const int wave_m = (w & 1) * 64;
    const int wave_n = (w >> 1) * 128;

    f32x4 acc[4][8] = {};

    // staging: row = 64 k bf16 = 128 B = 8 x 16B chunks; one gl_lds covers 8 rows
    const int srow = lane >> 3;
    const int scol = (lane & 7) * 8;
    const u16* gA = keysb + (size_t)(m0 + w * 32 + srow) * HDIM + scol;
    const u16* gB = uab   + (size_t)(n0 + w * 64 + srow) * HDIM + scol;
    u16* lA = As + (w * 32) * BK;          // wave-uniform bases
    u16* lB = Bs + (w * 64) * BK;

    const int fr = lane & 15;
    const int fq = lane >> 4;

    for (int k0 = 0; k0 < HDIM; k0 += BK) {
        __syncthreads();
        #pragma unroll
        for (int i = 0; i < 4; i++)        // 32 A rows per wave
            __builtin_amdgcn_global_load_lds((AS1 void*)(gA + k0 + i * 8 * HDIM),
                                             (AS3 void*)(lA + i * 8 * BK), 16, 0, 0);
        #pragma unroll
        for (int i = 0; i < 8; i++)        // 64 B rows per wave
            __builtin_amdgcn_global_load_lds((AS1 void*)(gB + k0 + i * 8 * HDIM),
                                             (AS3 void*)(lB + i * 8 * BK), 16, 0, 0);
        __syncthreads();

        #pragma unroll
        for (int j = 0; j < 2; j++) {      // two 32-k halves of the 64-k tile
            bf16x8 a[4], b[8];
            #pragma unroll
            for (int i = 0; i < 4; i++)
                a[i] = *(const bf16x8*)(As + (wave_m + i * 16 + fr) * BK + j * 32 + fq * 8);
            #pragma unroll
            for (int i = 0; i < 8; i++)
                b[i] = *(const bf16x8*)(Bs + (wave_n + i * 16 + fr) * BK + j * 32 + fq * 8);
            #pragma unroll
            for (int mi = 0; mi < 4; mi++)
                #pragma unroll
                for (int ni = 0; ni < 8; ni++)
                    acc[mi][ni] = __builtin_amdgcn_mfma_f32_16x16x32_bf16(a[mi], b[ni], acc[mi][ni], 0, 0, 0);
        }
    }

    // epilogue: h = tanh(acc + qb), partial score over 128 n-cols -> slice write
    const int bidx = m0 >> 11;   // BM=128 divides SEQ=2048
    float qv[8], vv[8];
    #pragma unroll
    for (int ni = 0; ni < 8; ni++) {
        int n_g = n0 + wave_n + ni * 16 + fr;
        qv[ni] = qb[bidx * HDIM + n_g];
        vv[ni] = vaw[n_g];
    }
    const int slice = blockIdx.x * 2 + (w >> 1);
    float* sl = sp + ((size_t)slice * BATCH + bidx) * SEQ;
    #pragma unroll
    for (int mi = 0; mi < 4; mi++) {
        #pragma unroll
        for (int r = 0; r < 4; r++) {
            float p = 0.f;
            #pragma unroll
            for (int ni = 0; ni < 8; ni++) {
                float x = acc[mi][ni][r] + qv[ni];
                float e = __expf(2.f * x);          // tanh = 1 - 2/(e^{2x}+1), NaN-free
                p += (1.f - 2.f / (e + 1.f)) * vv[ni];
            }
            p += __shfl_xor(p, 1);
            p += __shfl_xor(p, 2);
            p += __shfl_xor(p, 4);
            p += __shfl_xor(p, 8);
            if (fr == 0) {
                int s_g = (m0 + wave_m + mi * 16 + fq * 4 + r) & (SEQ - 1);
                sl[s_g] = p;
            }
        }
    }
}

// ---- softmax over SEQ per batch; sums 8 slices; zeroes ctx region ----
__global__ __launch_bounds__(256) void softmax_kernel(const float* __restrict__ sp,
                                                      float* __restrict__ weights,
                                                      float* __restrict__ ctx) {
    __shared__ float red[4];
    const int b = blockIdx.x;
    const int tid = threadIdx.x;
    float4 z = {0.f, 0.f, 0.f, 0.f};
    ((float4*)(ctx + b * HDIM))[tid] = z;       // zero context for atomics
    float v[8];
    float mx = -1e30f;
    #pragma unroll
    for (int i = 0; i < 8; i++) {
        int s = tid + i * 256;
        float a = 0.f;
        #pragma unroll
        for (int j = 0; j < NSLICE; j++) a += sp[((size_t)j * BATCH + b) * SEQ + s];
        v[i] = a;
        mx = fmaxf(mx, a);
    }
    #pragma unroll
    for (int m = 1; m < 64; m <<= 1) mx = fmaxf(mx, __shfl_xor(mx, m));
    if ((tid & 63) == 0) red[tid >> 6] = mx;
    __syncthreads();
    mx = fmaxf(fmaxf(red[0], red[1]), fmaxf(red[2], red[3]));
    float sum = 0.f;
    #pragma unroll
    for (int i = 0; i < 8; i++) { v[i] = __expf(v[i] - mx); sum += v[i]; }
    #pragma unroll
    for (int m = 1; m < 64; m <<= 1) sum += __shfl_xor(sum, m);
    __syncthreads();
    if ((tid & 63) == 0) red[tid >> 6] = sum;
    __syncthreads();
    sum = red[0] + red[1] + red[2] + red[3];
    float inv = 1.f / sum;
    #pragma unroll
    for (int i = 0; i < 8; i++) weights[b * SEQ + tid + i * 256] = v[i] * inv;
}

// ---- context[b][h] = sum_s w[b][s] * keysb[b][s][h] (bf16 keys) ----
// grid (BATCH, 8), block 256: each block covers 256 s-rows -> 16 atomics per
// ctx address total (was 64). Thread: h-group (tid&127)*8, s-half (tid>>7)*128.
__global__ __launch_bounds__(256) void context_kernel(const u16* __restrict__ keysb,
                                                      const float* __restrict__ weights,
                                                      float* __restrict__ ctx) {
    __shared__ float wsm[256];
    const int b = blockIdx.x;
    const int s0 = blockIdx.y * 256;
    const int tid = threadIdx.x;
    wsm[tid] = weights[b * SEQ + s0 + tid];
    __syncthreads();
    const int hq = tid & 127;
    const int sh = (tid >> 7) * 128;
    float a0 = 0.f, a1 = 0.f, a2 = 0.f, a3 = 0.f;
    float a4 = 0.f, a5 = 0.f, a6 = 0.f, a7 = 0.f;
    const uint4* kp = (const uint4*)(keysb + (size_t)b * SEQ * HDIM
                                     + (size_t)(s0 + sh) * HDIM) + hq;
    #pragma unroll 8
    for (int s = 0; s < 128; s++) {
        uint4 kv = kp[s * 128];            // row stride = 1024 u16 = 128 uint4
        float wv = wsm[sh + s];
        a0 += wv * __uint_as_float(kv.x << 16);
        a1 += wv * __uint_as_float(kv.x & 0xFFFF0000u);
        a2 += wv * __uint_as_float(kv.y << 16);
        a3 += wv * __uint_as_float(kv.y & 0xFFFF0000u);
        a4 += wv * __uint_as_float(kv.z << 16);
        a5 += wv * __uint_as_float(kv.z & 0xFFFF0000u);
        a6 += wv * __uint_as_float(kv.w << 16);
        a7 += wv * __uint_as_float(kv.w & 0xFFFF0000u);
    }
    float* o = ctx + b * HDIM + hq * 8;
    atomicAdd(o + 0, a0);
    atomicAdd(o + 1, a1);
    atomicAdd(o + 2, a2);
    atomicAdd(o + 3, a3);
    atomicAdd(o + 4, a4);
    atomicAdd(o + 5, a5);
    atomicAdd(o + 6, a6);
    atomicAdd(o + 7, a7);
}

extern "C" void kernel_launch(void* const* d_in, const int* in_sizes, int n_in,
                              void* d_out, int out_size, void* d_ws, size_t ws_size,
                              hipStream_t stream) {
    const float* query = (const float*)d_in[0];
    const float* keys  = (const float*)d_in[1];
    const float* Wa_w  = (const float*)d_in[2];
    const float* Wa_b  = (const float*)d_in[3];
    const float* Ua_w  = (const float*)d_in[4];
    const float* Ua_b  = (const float*)d_in[5];
    const float* Va_w  = (const float*)d_in[6];
    // Va_b unused: softmax is shift-invariant.
    float* out = (float*)d_out;   // [0, 32768) context, [32768, 98304) weights

    char* ws = (char*)d_ws;
    u16*  keysb = (u16*)ws;                                     // 134217728 B
    u16*  uab   = (u16*)(ws + 134217728);                       //   2097152 B
    float* qb   = (float*)(ws + 134217728 + 2097152);           //    131072 B
    float* sp   = (float*)(ws + 134217728 + 2097152 + 131072);  //   2097152 B

    cvt_kernel<<<(BATCH * SEQ * HDIM) / 2048, 256, 0, stream>>>(keys, keysb);
    cvt_kernel<<<(HDIM * HDIM) / 2048, 256, 0, stream>>>(Ua_w, uab);
    qb_kernel<<<dim3(BATCH, HDIM / 64), 256, 0, stream>>>(query, Wa_w, Wa_b, Ua_b, qb);
    gemm_score_kernel<<<dim3(HDIM / BN, M_TOTAL / BM), 256, 0, stream>>>(keysb, uab, qb, Va_w, sp);
    softmax_kernel<<<BATCH, 256, 0, stream>>>(sp, out + BATCH * HDIM, out);
    context_kernel<<<dim3(BATCH, 8), 256, 0, stream>>>(keysb, out + BATCH * HDIM, out);
}